// Round 3
// baseline (656.146 us; speedup 1.0000x reference)
//
#include <hip/hip_runtime.h>

#define DEVFN __device__ __forceinline__

static constexpr int cB  = 16;
static constexpr int cS  = 1024;
static constexpr int cD  = 1024;
static constexpr int cPE = 20;
static constexpr int cG  = 80;   // 4*PE

typedef float  floatx2  __attribute__((ext_vector_type(2)));
typedef float  floatx4  __attribute__((ext_vector_type(4)));
typedef float  floatx16 __attribute__((ext_vector_type(16)));
typedef short  short8   __attribute__((ext_vector_type(8)));
typedef unsigned uintx2 __attribute__((ext_vector_type(2)));

DEVFN unsigned pack_bf(float a, float b) {
  union { float f; unsigned u; } ua, ub; ua.f = a; ub.f = b;
  return (ua.u >> 16) | (ub.u & 0xffff0000u);
}

// ---------------------------------------------------------------------------
// K1: xgT[b][g][t] = (x @ W_ih^T + b_ih + b_hh) * gate_scale(g), transposed
//     for k2's streaming loads. gate_scale = 2*log2e for g in [40,60) (the
//     tanh gate), log2e otherwise.
//     + fused emit of x transposed to bf16: xbf_t[b][d][s] for k4.
// Tile: 64 rows x 80 gates, K-chunks of 64. Grid = 256 blocks.
// ---------------------------------------------------------------------------
static constexpr int K1_XS = 68;  // LDS row stride (floats)

__global__ __launch_bounds__(256) void k1_xg(
    const float* __restrict__ x, const float* __restrict__ W_ih,
    const float* __restrict__ b_ih, const float* __restrict__ b_hh,
    float* __restrict__ xgT, unsigned short* __restrict__ xbf_t, int use_bf)
{
  __shared__ float xs[64 * K1_XS];   // 17408 B
  __shared__ float wsm[80 * K1_XS];  // 21760 B

  const int t  = threadIdx.x;
  const int rg = t >> 4, cg = t & 15;
  const int r0 = rg * 4, c0 = cg * 5;
  const int row0 = blockIdx.x * 64;
  const int b  = row0 >> 10;
  const int s0 = row0 & 1023;

  floatx2 acc[4][5];
#pragma unroll
  for (int q = 0; q < 4; ++q)
#pragma unroll
    for (int cc = 0; cc < 5; ++cc) { acc[q][cc].x = 0.f; acc[q][cc].y = 0.f; }

  for (int kc = 0; kc < 16; ++kc) {
    const int k0 = kc * 64;
    // ---- stage x tile: 64 rows x 64 k ------------------------------------
    {
      const int sr = t >> 2, sc = t & 3;
      const float4* src = (const float4*)(x + (size_t)(row0 + sr) * cD + k0 + sc * 16);
      float4 v0 = src[0], v1 = src[1], v2 = src[2], v3 = src[3];
      float4* dst = (float4*)&xs[sr * K1_XS + sc * 16];
      dst[0] = v0; dst[1] = v1; dst[2] = v2; dst[3] = v3;
    }
    // ---- stage W tile: 80 gates x 64 k -----------------------------------
#pragma unroll
    for (int q = 0; q < 5; ++q) {
      const int id = t + q * 256;          // 0..1279
      const int g = id >> 4, c4 = id & 15;
      float4 wv = *(const float4*)(W_ih + (size_t)g * cD + k0 + c4 * 4);
      *(float4*)&wsm[g * K1_XS + c4 * 4] = wv;
    }
    __syncthreads();

    // ---- transposed bf16 emit: xbf_t[b][k0+dl][s0 + 16*sc4 + e] ----------
    if (use_bf) {
      const int dl = t >> 2, sc4 = t & 3;
      float v[16];
#pragma unroll
      for (int e = 0; e < 16; ++e) v[e] = xs[(sc4 * 16 + e) * K1_XS + dl];
      unsigned u[8];
#pragma unroll
      for (int p = 0; p < 8; ++p) u[p] = pack_bf(v[2 * p], v[2 * p + 1]);
      unsigned short* dstp = xbf_t + ((size_t)(b * cD + k0 + dl)) * cS + s0 + sc4 * 16;
      *(uint4*)dstp       = make_uint4(u[0], u[1], u[2], u[3]);
      *(uint4*)(dstp + 8) = make_uint4(u[4], u[5], u[6], u[7]);
    }

    // ---- compute: 32 x (9 ds_read_b64 + 20 pk_fma) -----------------------
#pragma unroll 4
    for (int k2 = 0; k2 < 32; ++k2) {
      floatx2 xv[4], wv[5];
#pragma unroll
      for (int q = 0; q < 4; ++q)
        xv[q] = *(const floatx2*)&xs[(r0 + q) * K1_XS + 2 * k2];
#pragma unroll
      for (int cc = 0; cc < 5; ++cc)
        wv[cc] = *(const floatx2*)&wsm[(c0 + cc) * K1_XS + 2 * k2];
#pragma unroll
      for (int q = 0; q < 4; ++q)
#pragma unroll
        for (int cc = 0; cc < 5; ++cc)
          acc[q][cc] += xv[q] * wv[cc];
    }
    __syncthreads();
  }

  // ---- epilogue: scaled, biased, transposed stores (float4 over t) -------
#pragma unroll
  for (int cc = 0; cc < 5; ++cc) {
    const int g = c0 + cc;
    const float sc = (g >= 40 && g < 60) ? 2.88539008f : 1.44269504f;
    const float bs = b_ih[g] + b_hh[g];
    float4 v;
    v.x = (acc[0][cc].x + acc[0][cc].y + bs) * sc;
    v.y = (acc[1][cc].x + acc[1][cc].y + bs) * sc;
    v.z = (acc[2][cc].x + acc[2][cc].y + bs) * sc;
    v.w = (acc[3][cc].x + acc[3][cc].y + bs) * sc;
    *(float4*)&xgT[((size_t)(b * cG + g)) * cS + s0 + r0] = v;
  }
}

// ---------------------------------------------------------------------------
// K2: LSTM scan, fully in-register, TWO batches per wave (grid = 8 waves).
// Round-2 post-mortem: single-chain version ran 431 cy/step with issue floor
// ~142 cy -> ~290 cy/step of exposed latency (trans ops + SGPR hazards).
// Two independent batch chains interleaved in one wave fill those stalls.
//
// Lane layout per batch (j = lane&31, clamped to 19):
//   low half  (lane<32):  A-stream = i_j (row j),    B-stream = g_j (row 40+j)
//   high half (lane>=32): A-stream = f_j (row 20+j), B-stream = o_j (row 60+j)
// Streams from xgT are pre-scaled+biased (log2e; 2*log2e for g rows).
// Unified activation: sigmoid = e/(e+1), tanh = (e-1)/(e+1), e = exp2(gate).
//  - gate gather: v_permlane32_swap(act,act): ret.x = low-half bcast (i|g),
//    ret.y = high-half bcast (f|o). Both halves compute c,h redundantly.
//  - h broadcast: 20x v_readlane -> 10 SGPR pairs, fed to v_pk_fma_f32.
// No LDS, no barriers. W_hh registers shared across the two batches.
// Gate-side fmin clamps dropped (|gate*log2e| <~ 12 for this data); the c
// chain keeps its clamp (c can random-walk large -> exp2 overflow -> NaN).
// ---------------------------------------------------------------------------
DEVFN void bcast_h(int hbits, unsigned long long* hp) {
  const unsigned l0  = (unsigned)__builtin_amdgcn_readlane(hbits, 0);
  const unsigned l1  = (unsigned)__builtin_amdgcn_readlane(hbits, 1);
  const unsigned l2  = (unsigned)__builtin_amdgcn_readlane(hbits, 2);
  const unsigned l3  = (unsigned)__builtin_amdgcn_readlane(hbits, 3);
  const unsigned l4  = (unsigned)__builtin_amdgcn_readlane(hbits, 4);
  const unsigned l5  = (unsigned)__builtin_amdgcn_readlane(hbits, 5);
  const unsigned l6  = (unsigned)__builtin_amdgcn_readlane(hbits, 6);
  const unsigned l7  = (unsigned)__builtin_amdgcn_readlane(hbits, 7);
  const unsigned l8  = (unsigned)__builtin_amdgcn_readlane(hbits, 8);
  const unsigned l9  = (unsigned)__builtin_amdgcn_readlane(hbits, 9);
  const unsigned l10 = (unsigned)__builtin_amdgcn_readlane(hbits, 10);
  const unsigned l11 = (unsigned)__builtin_amdgcn_readlane(hbits, 11);
  const unsigned l12 = (unsigned)__builtin_amdgcn_readlane(hbits, 12);
  const unsigned l13 = (unsigned)__builtin_amdgcn_readlane(hbits, 13);
  const unsigned l14 = (unsigned)__builtin_amdgcn_readlane(hbits, 14);
  const unsigned l15 = (unsigned)__builtin_amdgcn_readlane(hbits, 15);
  const unsigned l16 = (unsigned)__builtin_amdgcn_readlane(hbits, 16);
  const unsigned l17 = (unsigned)__builtin_amdgcn_readlane(hbits, 17);
  const unsigned l18 = (unsigned)__builtin_amdgcn_readlane(hbits, 18);
  const unsigned l19 = (unsigned)__builtin_amdgcn_readlane(hbits, 19);
  hp[0] = (unsigned long long)l0  | ((unsigned long long)l1  << 32);
  hp[1] = (unsigned long long)l2  | ((unsigned long long)l3  << 32);
  hp[2] = (unsigned long long)l4  | ((unsigned long long)l5  << 32);
  hp[3] = (unsigned long long)l6  | ((unsigned long long)l7  << 32);
  hp[4] = (unsigned long long)l8  | ((unsigned long long)l9  << 32);
  hp[5] = (unsigned long long)l10 | ((unsigned long long)l11 << 32);
  hp[6] = (unsigned long long)l12 | ((unsigned long long)l13 << 32);
  hp[7] = (unsigned long long)l14 | ((unsigned long long)l15 << 32);
  hp[8] = (unsigned long long)l16 | ((unsigned long long)l17 << 32);
  hp[9] = (unsigned long long)l18 | ((unsigned long long)l19 << 32);
}

__global__ __launch_bounds__(64) void k2_lstm(
    const float* __restrict__ xgT, const float* __restrict__ W_hh,
    float* __restrict__ hbuf)
{
  const int b0   = blockIdx.x * 2;
  const int b1   = b0 + 1;
  const int lane = threadIdx.x;
  const int half = lane >> 5;
  const int l31  = lane & 31;
  const int j    = (l31 < cPE) ? l31 : (cPE - 1);
  const float LOG2E = 1.44269504f, TWOLOG2E = 2.88539008f;

  const int rowA = half ? (20 + j) : j;          // f_j : i_j   (both sigmoid)
  const int rowB = half ? (60 + j) : (40 + j);   // o_j : g_j   (sigmoid : tanh)
  const float sB   = half ? LOG2E : TWOLOG2E;    // pre-scale for W rows
  const float subB = half ? 0.f : 1.f;           // tanh numerator: e-1

  floatx2 wA[10], wB[10];    // shared across both batches
#pragma unroll
  for (int p = 0; p < 10; ++p) {
    wA[p].x = W_hh[rowA * cPE + 2 * p]     * LOG2E;
    wA[p].y = W_hh[rowA * cPE + 2 * p + 1] * LOG2E;
    wB[p].x = W_hh[rowB * cPE + 2 * p]     * sB;
    wB[p].y = W_hh[rowB * cPE + 2 * p + 1] * sB;
  }

  const float* baseA0 = xgT + ((size_t)(b0 * cG + rowA)) * cS;
  const float* baseB0 = xgT + ((size_t)(b0 * cG + rowB)) * cS;
  const float* baseA1 = xgT + ((size_t)(b1 * cG + rowA)) * cS;
  const float* baseB1 = xgT + ((size_t)(b1 * cG + rowB)) * cS;

  // 4-slot rotation: slot s holds quad q0+s; reload for q+4 (16 steps ahead).
  // Trailing prefetches read <=64B past xgT's end -> hbuf region (safe).
  float4 bufA0[4], bufB0[4], bufA1[4], bufB1[4];
#pragma unroll
  for (int s = 0; s < 4; ++s) {
    bufA0[s] = *(const float4*)(baseA0 + s * 4);
    bufB0[s] = *(const float4*)(baseB0 + s * 4);
    bufA1[s] = *(const float4*)(baseA1 + s * 4);
    bufB1[s] = *(const float4*)(baseB1 + s * 4);
  }

  unsigned long long hp0[10], hp1[10];
#pragma unroll
  for (int p = 0; p < 10; ++p) { hp0[p] = 0ull; hp1[p] = 0ull; }

  float c0 = 0.f, c1 = 0.f;
  float* hb0 = hbuf + (size_t)b0 * cS * cPE + j;
  float* hb1 = hbuf + (size_t)b1 * cS * cPE + j;

  for (int q0 = 0; q0 < 256; q0 += 4) {
#pragma unroll
    for (int s = 0; s < 4; ++s) {
      const int q = q0 + s;
      const float4 gA40 = bufA0[s], gB40 = bufB0[s];
      const float4 gA41 = bufA1[s], gB41 = bufB1[s];
      bufA0[s] = *(const float4*)(baseA0 + (q + 4) * 4);
      bufB0[s] = *(const float4*)(baseB0 + (q + 4) * 4);
      bufA1[s] = *(const float4*)(baseA1 + (q + 4) * 4);
      bufB1[s] = *(const float4*)(baseB1 + (q + 4) * 4);
#pragma unroll
      for (int e = 0; e < 4; ++e) {
        const float geA0 = (e == 0) ? gA40.x : (e == 1) ? gA40.y : (e == 2) ? gA40.z : gA40.w;
        const float geB0 = (e == 0) ? gB40.x : (e == 1) ? gB40.y : (e == 2) ? gB40.z : gB40.w;
        const float geA1 = (e == 0) ? gA41.x : (e == 1) ? gA41.y : (e == 2) ? gA41.z : gA41.w;
        const float geB1 = (e == 0) ? gB41.x : (e == 1) ? gB41.y : (e == 2) ? gB41.z : gB41.w;

        // ---- dots: 40 packed fma (2 batches), h from SGPR pairs ----------
        floatx2 aA0_0, aA1_0, aB0_0, aB1_0, aA0_1, aA1_1, aB0_1, aB1_1;
        aA0_0.x = geA0; aA0_0.y = 0.f; aA1_0.x = 0.f; aA1_0.y = 0.f;
        aB0_0.x = geB0; aB0_0.y = 0.f; aB1_0.x = 0.f; aB1_0.y = 0.f;
        aA0_1.x = geA1; aA0_1.y = 0.f; aA1_1.x = 0.f; aA1_1.y = 0.f;
        aB0_1.x = geB1; aB0_1.y = 0.f; aB1_1.x = 0.f; aB1_1.y = 0.f;
#pragma unroll
        for (int p = 0; p < 5; ++p) {
          asm("v_pk_fma_f32 %0, %1, %2, %0" : "+v"(aA0_0) : "v"(wA[p]),     "s"(hp0[p]));
          asm("v_pk_fma_f32 %0, %1, %2, %0" : "+v"(aA0_1) : "v"(wA[p]),     "s"(hp1[p]));
          asm("v_pk_fma_f32 %0, %1, %2, %0" : "+v"(aA1_0) : "v"(wA[5 + p]), "s"(hp0[5 + p]));
          asm("v_pk_fma_f32 %0, %1, %2, %0" : "+v"(aA1_1) : "v"(wA[5 + p]), "s"(hp1[5 + p]));
          asm("v_pk_fma_f32 %0, %1, %2, %0" : "+v"(aB0_0) : "v"(wB[p]),     "s"(hp0[p]));
          asm("v_pk_fma_f32 %0, %1, %2, %0" : "+v"(aB0_1) : "v"(wB[p]),     "s"(hp1[p]));
          asm("v_pk_fma_f32 %0, %1, %2, %0" : "+v"(aB1_0) : "v"(wB[5 + p]), "s"(hp0[5 + p]));
          asm("v_pk_fma_f32 %0, %1, %2, %0" : "+v"(aB1_1) : "v"(wB[5 + p]), "s"(hp1[5 + p]));
        }
        const float gAv0 = (aA0_0.x + aA0_0.y) + (aA1_0.x + aA1_0.y);
        const float gBv0 = (aB0_0.x + aB0_0.y) + (aB1_0.x + aB1_0.y);
        const float gAv1 = (aA0_1.x + aA0_1.y) + (aA1_1.x + aA1_1.y);
        const float gBv1 = (aB0_1.x + aB0_1.y) + (aB1_1.x + aB1_1.y);

        // ---- activations (no gate clamp: |g*log2e| <= ~12 for this data) -
        const float eA0   = __builtin_amdgcn_exp2f(gAv0);
        const float eA1   = __builtin_amdgcn_exp2f(gAv1);
        const float eB0   = __builtin_amdgcn_exp2f(gBv0);
        const float eB1   = __builtin_amdgcn_exp2f(gBv1);
        const float actA0 = eA0 * __builtin_amdgcn_rcpf(eA0 + 1.f);
        const float actA1 = eA1 * __builtin_amdgcn_rcpf(eA1 + 1.f);
        const float actB0 = (eB0 - subB) * __builtin_amdgcn_rcpf(eB0 + 1.f);
        const float actB1 = (eB1 - subB) * __builtin_amdgcn_rcpf(eB1 + 1.f);

        // ---- half-swap gathers: .x = low bcast (i|g), .y = high (f|o) ----
        union { float f; unsigned u; } ca0, cb0, ca1, cb1;
        ca0.f = actA0; cb0.f = actB0; ca1.f = actA1; cb1.f = actB1;
        uintx2 rA0 = __builtin_amdgcn_permlane32_swap(ca0.u, ca0.u, false, false);
        uintx2 rB0 = __builtin_amdgcn_permlane32_swap(cb0.u, cb0.u, false, false);
        uintx2 rA1 = __builtin_amdgcn_permlane32_swap(ca1.u, ca1.u, false, false);
        uintx2 rB1 = __builtin_amdgcn_permlane32_swap(cb1.u, cb1.u, false, false);
        union { unsigned u; float f; } vf0, vi0, vg0, vo0, vf1, vi1, vg1, vo1;
        vi0.u = rA0.x; vf0.u = rA0.y; vg0.u = rB0.x; vo0.u = rB0.y;
        vi1.u = rA1.x; vf1.u = rA1.y; vg1.u = rB1.x; vo1.u = rB1.y;

        // ---- state update (identical on both halves) ---------------------
        c0 = vf0.f * c0 + vi0.f * vg0.f;
        c1 = vf1.f * c1 + vi1.f * vg1.f;
        const float ec0 = __builtin_amdgcn_exp2f(fminf(TWOLOG2E * c0, 30.f));
        const float ec1 = __builtin_amdgcn_exp2f(fminf(TWOLOG2E * c1, 30.f));
        const float th0 = (ec0 - 1.f) * __builtin_amdgcn_rcpf(ec0 + 1.f);
        const float th1 = (ec1 - 1.f) * __builtin_amdgcn_rcpf(ec1 + 1.f);
        const float hj0 = vo0.f * th0;
        const float hj1 = vo1.f * th1;

        if (lane < cPE) {
          hb0[(size_t)(q * 4 + e) * cPE] = hj0;
          hb1[(size_t)(q * 4 + e) * cPE] = hj1;
        }

        // ---- broadcast h -> SGPR pairs (both batches) --------------------
        union { float f; unsigned u; } ch0, ch1;
        ch0.f = hj0; ch1.f = hj1;
        bcast_h((int)ch0.u, hp0);
        bcast_h((int)ch1.u, hp1);
      }
    }
  }
}

// ---------------------------------------------------------------------------
// K3a: muwT[g][r] = relu(h@W_mu^T + b_mu), sigma = sigmoid(h@W_sig^T + b_sig)
// SoA output for the scan kernel. Grid: 64 blocks x 256.
// ---------------------------------------------------------------------------
__global__ __launch_bounds__(256) void k3a_muw(
    const float* __restrict__ hbuf,
    const float* __restrict__ W_mu, const float* __restrict__ b_mu,
    const float* __restrict__ W_sig, const float* __restrict__ b_sig,
    float* __restrict__ muwT, float* __restrict__ sigma)
{
  __shared__ float sw[84];
  const int t = threadIdx.x;
  if (t < 60) sw[t] = W_mu[t];
  else if (t < 80) sw[t] = W_sig[t - 60];
  else if (t < 83) sw[t] = b_mu[t - 80];
  else if (t == 83) sw[t] = b_sig[0];
  __syncthreads();

  const int r = blockIdx.x * 256 + t;
  const float4* hp = (const float4*)(hbuf + (size_t)r * cPE);
  float h[20];
#pragma unroll
  for (int q2 = 0; q2 < 5; ++q2) {
    float4 v = hp[q2];
    h[4 * q2] = v.x; h[4 * q2 + 1] = v.y; h[4 * q2 + 2] = v.z; h[4 * q2 + 3] = v.w;
  }
  float m0 = sw[80], m1 = sw[81], m2 = sw[82], sg = sw[83];
#pragma unroll
  for (int p = 0; p < 20; ++p) {
    m0 += sw[p]      * h[p];
    m1 += sw[20 + p] * h[p];
    m2 += sw[40 + p] * h[p];
    sg += sw[60 + p] * h[p];
  }
  muwT[r]                 = fmaxf(m0, 0.f);
  muwT[cB * cS + r]       = fmaxf(m1, 0.f);
  muwT[2 * cB * cS + r]   = fmaxf(m2, 0.f);
  sigma[r] = __builtin_amdgcn_rcpf(1.f + __builtin_amdgcn_exp2f(-1.44269504f * sg));
}

// ---------------------------------------------------------------------------
// K3b: sequential mu recurrence, 16 chains (one lane each), float4 prefetch.
// ---------------------------------------------------------------------------
__global__ __launch_bounds__(64) void k3b_mu(
    const float* __restrict__ muwT, float* __restrict__ mu)
{
  const int t = threadIdx.x;
  if (t >= cB) return;
  const float* s0p = muwT + (size_t)t * cS;
  const float* s1p = muwT + cB * cS + (size_t)t * cS;
  const float* s2p = muwT + 2 * cB * cS + (size_t)t * cS;
  float* mb = mu + (size_t)t * cS;
  const float inv = 1.f / (float)cS;

  float4 a0 = *(const float4*)(s0p);
  float4 a1 = *(const float4*)(s1p);
  float4 a2 = *(const float4*)(s2p);
  float4 n0 = *(const float4*)(s0p + 4);
  float4 n1 = *(const float4*)(s1p + 4);
  float4 n2 = *(const float4*)(s2p + 4);

  float m = 0.f;
  for (int t4 = 0; t4 < 256; ++t4) {
    float4 w0 = a0, w1 = a1, w2 = a2;
    a0 = n0; a1 = n1; a2 = n2;
    if (t4 < 254) {
      n0 = *(const float4*)(s0p + t4 * 4 + 8);
      n1 = *(const float4*)(s1p + t4 * 4 + 8);
      n2 = *(const float4*)(s2p + t4 * 4 + 8);
    }
    const int tt = t4 * 4;
    m = w0.x * m + (w1.x + w2.x * (float)(tt + 1)) * inv; mb[tt]     = m;
    m = w0.y * m + (w1.y + w2.y * (float)(tt + 2)) * inv; mb[tt + 1] = m;
    m = w0.z * m + (w1.z + w2.z * (float)(tt + 3)) * inv; mb[tt + 2] = m;
    m = w0.w * m + (w1.w + w2.w * (float)(tt + 4)) * inv; mb[tt + 3] = m;
  }
}

// ---------------------------------------------------------------------------
// K4: fused positional attention with 32x32x16 bf16 MFMA.
// context[b,j,:] = (sum_{i<=j} w_ji * x[b,i,:]) / max(||w_j||, 1e-12)
// x staged d-major in LDS (from xbf_t) so each B-fragment is one
// ds_read_b128. w generated on the fly in MFMA A-fragment layout.
// Block 256 thr = 4 waves: wave = (jh, dh); tile 64 j x 128 d; K-step 32 i.
// ---------------------------------------------------------------------------
static constexpr int TJ = 64, TD = 128, KI = 32, RS = 40;  // RS: LDS row stride (shorts)

__global__ __launch_bounds__(256) void k4_attn(
    const float* __restrict__ x, const unsigned short* __restrict__ xbf_t,
    int use_bf, const float* __restrict__ mu, const float* __restrict__ sigma,
    float* __restrict__ out)
{
  __shared__ unsigned short xsT[TD * RS];   // 10240 B
  __shared__ float snrm[2][32];
  __shared__ float sscl[2][32];

  const int b   = blockIdx.z;
  const int jt0 = blockIdx.x * TJ;
  const int dt0 = blockIdx.y * TD;
  const int tid = threadIdx.x;
  const int wave = tid >> 6, lane = tid & 63;
  const int jh = wave & 1, dh = wave >> 1;
  const int n32 = lane & 31, half = lane >> 5;
  const int jrow = jt0 + jh * 32 + n32;

  const float muv  = mu[b * cS + jrow];
  const float sg   = sigma[b * cS + jrow];
  const float invj = 1.f / (float)(jrow + 1);
  const float ce   = -0.72134752f / (sg * sg);   // -log2(e)/(2*sigma^2)

  float nrm2 = 0.f;
  floatx16 acc0 = (floatx16)0.f, acc1 = (floatx16)0.f;

  const int iend = jt0 + TJ;
  for (int i0 = 0; i0 < iend; i0 += KI) {
    __syncthreads();
    // ---- stage xsT[d][i] : 128 d-rows x 32 i (bf16) ----------------------
    if (use_bf) {
#pragma unroll
      for (int q = 0; q < 2; ++q) {
        const int cc = tid + q * 256;
        const int dl = cc >> 2, part = cc & 3;
        uint4 v = *(const uint4*)(xbf_t + ((size_t)(b * cD + dt0 + dl)) * cS + i0 + part * 8);
        *(uint4*)&xsT[dl * RS + part * 8] = v;
      }
    } else {
#pragma unroll
      for (int q = 0; q < 2; ++q) {
        const int cc = tid + q * 256;
        const int i = cc & 31, d8 = cc >> 5;
        const float* xp = x + ((size_t)(b * cS + i0 + i)) * cD + dt0 + d8 * 8;
        float4 f0 = *(const float4*)xp;
        float4 f1 = *(const float4*)(xp + 4);
        float vv[8] = {f0.x, f0.y, f0.z, f0.w, f1.x, f1.y, f1.z, f1.w};
#pragma unroll
        for (int e = 0; e < 8; ++e) {
          union { float f; unsigned u; } cv; cv.f = vv[e];
          xsT[(d8 * 8 + e) * RS + i] = (unsigned short)(cv.u >> 16);
        }
      }
    }
    __syncthreads();

    // ---- A fragments (w values), kc = 0,1 --------------------------------
    short8 af0, af1;
#pragma unroll
    for (int kc = 0; kc < 2; ++kc) {
      short8 af;
#pragma unroll
      for (int e = 0; e < 8; ++e) {
        const int ig = i0 + kc * 16 + half * 8 + e;
        const float d = fmaf((float)ig, invj, -muv);
        float w = __builtin_amdgcn_exp2f(ce * d * d);
        w = (ig <= jrow) ? w : 0.f;
        nrm2 += w * w;
        union { float f; unsigned u; } cv; cv.f = w;
        af[e] = (short)(cv.u >> 16);
      }
      if (kc == 0) af0 = af; else af1 = af;
    }

    // ---- B fragments (one ds_read_b128 each) + MFMA ----------------------
    const int rbase = dh * 64 + n32;
    short8 b00 = *(const short8*)&xsT[(rbase)      * RS + half * 8];
    short8 b01 = *(const short8*)&xsT[(rbase)      * RS + 16 + half * 8];
    short8 b10 = *(const short8*)&xsT[(rbase + 32) * RS + half * 8];
    short8 b11 = *(const short8*)&xsT[(rbase + 32) * RS + 16 + half * 8];
    acc0 = __builtin_amdgcn_mfma_f32_32x32x16_bf16(af0, b00, acc0, 0, 0, 0);
    acc0 = __builtin_amdgcn_mfma_f32_32x32x16_bf16(af1, b01, acc0, 0, 0, 0);
    acc1 = __builtin_amdgcn_mfma_f32_32x32x16_bf16(af0, b10, acc1, 0, 0, 0);
    acc1 = __builtin_amdgcn_mfma_f32_32x32x16_bf16(af1, b11, acc1, 0, 0, 0);
  }

  // ---- norms --------------------------------------------------------------
  nrm2 += __shfl_xor(nrm2, 32);
  if (wave < 2 && half == 0) snrm[jh][n32] = nrm2;
  __syncthreads();
  if (tid < 64)
    sscl[tid >> 5][tid & 31] =
        __builtin_amdgcn_rcpf(fmaxf(sqrtf(snrm[tid >> 5][tid & 31]), 1e-12f));
  __syncthreads();

  float srow[16];
#pragma unroll
  for (int reg = 0; reg < 16; ++reg) {
    const int row = (reg & 3) + 8 * (reg >> 2) + 4 * half;
    srow[reg] = sscl[jh][row];
  }
#pragma unroll
  for (int reg = 0; reg < 16; ++reg) {
    const int row = (reg & 3) + 8 * (reg >> 2) + 4 * half;
    const int jg = jt0 + jh * 32 + row;
    const int d0 = dt0 + dh * 64 + n32;
    out[((size_t)(b * cS + jg)) * cD + d0]      = acc0[reg] * srow[reg];
    out[((size_t)(b * cS + jg)) * cD + d0 + 32] = acc1[reg] * srow[reg];
  }
}

// ---------------------------------------------------------------------------
extern "C" void kernel_launch(void* const* d_in, const int* in_sizes, int n_in,
                              void* d_out, int out_size, void* d_ws, size_t ws_size,
                              hipStream_t stream) {
  const float* x     = (const float*)d_in[0];
  const float* W_ih  = (const float*)d_in[1];
  const float* W_hh  = (const float*)d_in[2];
  const float* b_ih  = (const float*)d_in[3];
  const float* b_hh  = (const float*)d_in[4];
  const float* W_mu  = (const float*)d_in[5];
  const float* b_mu  = (const float*)d_in[6];
  const float* W_sig = (const float*)d_in[7];
  const float* b_sig = (const float*)d_in[8];
  float* out = (float*)d_out;

  char* ws = (char*)d_ws;
  const size_t off_xg  = 0;                                   // 16*80*1024*4
  const size_t off_h   = off_xg  + (size_t)cB*cS*cG*4;
  const size_t off_muw = off_h   + (size_t)cB*cS*cPE*4;
  const size_t off_sig = off_muw + (size_t)cB*cS*3*4;
  const size_t off_mu  = off_sig + (size_t)cB*cS*4;
  const size_t off_xbf = off_mu  + (size_t)cB*cS*4;
  const size_t need_bf = off_xbf + (size_t)cB*cS*cD*2;

  float* xgT   = (float*)(ws + off_xg);
  float* hbuf  = (float*)(ws + off_h);
  float* muwT  = (float*)(ws + off_muw);
  float* sigma = (float*)(ws + off_sig);
  float* mu    = (float*)(ws + off_mu);
  unsigned short* xbf_t = (unsigned short*)(ws + off_xbf);
  const int use_bf = (ws_size >= need_bf) ? 1 : 0;

  k1_xg  <<<dim3(cB * cS / 64), dim3(256), 0, stream>>>(x, W_ih, b_ih, b_hh, xgT, xbf_t, use_bf);
  k2_lstm<<<dim3(cB / 2),       dim3(64),  0, stream>>>(xgT, W_hh, hbuf);
  k3a_muw<<<dim3(cB * cS / 256), dim3(256), 0, stream>>>(hbuf, W_mu, b_mu, W_sig, b_sig, muwT, sigma);
  k3b_mu <<<dim3(1),            dim3(64),  0, stream>>>(muwT, mu);
  k4_attn<<<dim3(cS/TJ, cD/TD, cB), dim3(256), 0, stream>>>(x, xbf_t, use_bf, mu, sigma, out);
}

// Round 4
// 470.978 us; speedup vs baseline: 1.3932x; 1.3932x over previous
//
#include <hip/hip_runtime.h>

#define DEVFN __device__ __forceinline__

static constexpr int cB  = 16;
static constexpr int cS  = 1024;
static constexpr int cD  = 1024;
static constexpr int cPE = 20;
static constexpr int cG  = 80;   // 4*PE

typedef float  floatx2  __attribute__((ext_vector_type(2)));
typedef float  floatx4  __attribute__((ext_vector_type(4)));
typedef float  floatx16 __attribute__((ext_vector_type(16)));
typedef short  short8   __attribute__((ext_vector_type(8)));
typedef unsigned uintx2 __attribute__((ext_vector_type(2)));

DEVFN unsigned pack_bf(float a, float b) {
  union { float f; unsigned u; } ua, ub; ua.f = a; ub.f = b;
  return (ua.u >> 16) | (ub.u & 0xffff0000u);
}

// ---------------------------------------------------------------------------
// K1: xgT[b][g][t] = (x @ W_ih^T + b_ih + b_hh) * gate_scale(g), transposed
//     for k2's streaming loads. gate_scale = 2*log2e for g in [40,60) (the
//     tanh gate), log2e otherwise.
//     + fused emit of x transposed to bf16: xbf_t[b][d][s] for k4.
// Tile: 64 rows x 80 gates, K-chunks of 64. Grid = 256 blocks.
// ---------------------------------------------------------------------------
static constexpr int K1_XS = 68;  // LDS row stride (floats)

__global__ __launch_bounds__(256) void k1_xg(
    const float* __restrict__ x, const float* __restrict__ W_ih,
    const float* __restrict__ b_ih, const float* __restrict__ b_hh,
    float* __restrict__ xgT, unsigned short* __restrict__ xbf_t, int use_bf)
{
  __shared__ float xs[64 * K1_XS];   // 17408 B
  __shared__ float wsm[80 * K1_XS];  // 21760 B

  const int t  = threadIdx.x;
  const int rg = t >> 4, cg = t & 15;
  const int r0 = rg * 4, c0 = cg * 5;
  const int row0 = blockIdx.x * 64;
  const int b  = row0 >> 10;
  const int s0 = row0 & 1023;

  floatx2 acc[4][5];
#pragma unroll
  for (int q = 0; q < 4; ++q)
#pragma unroll
    for (int cc = 0; cc < 5; ++cc) { acc[q][cc].x = 0.f; acc[q][cc].y = 0.f; }

  for (int kc = 0; kc < 16; ++kc) {
    const int k0 = kc * 64;
    // ---- stage x tile: 64 rows x 64 k ------------------------------------
    {
      const int sr = t >> 2, sc = t & 3;
      const float4* src = (const float4*)(x + (size_t)(row0 + sr) * cD + k0 + sc * 16);
      float4 v0 = src[0], v1 = src[1], v2 = src[2], v3 = src[3];
      float4* dst = (float4*)&xs[sr * K1_XS + sc * 16];
      dst[0] = v0; dst[1] = v1; dst[2] = v2; dst[3] = v3;
    }
    // ---- stage W tile: 80 gates x 64 k -----------------------------------
#pragma unroll
    for (int q = 0; q < 5; ++q) {
      const int id = t + q * 256;          // 0..1279
      const int g = id >> 4, c4 = id & 15;
      float4 wv = *(const float4*)(W_ih + (size_t)g * cD + k0 + c4 * 4);
      *(float4*)&wsm[g * K1_XS + c4 * 4] = wv;
    }
    __syncthreads();

    // ---- transposed bf16 emit: xbf_t[b][k0+dl][s0 + 16*sc4 + e] ----------
    if (use_bf) {
      const int dl = t >> 2, sc4 = t & 3;
      float v[16];
#pragma unroll
      for (int e = 0; e < 16; ++e) v[e] = xs[(sc4 * 16 + e) * K1_XS + dl];
      unsigned u[8];
#pragma unroll
      for (int p = 0; p < 8; ++p) u[p] = pack_bf(v[2 * p], v[2 * p + 1]);
      unsigned short* dstp = xbf_t + ((size_t)(b * cD + k0 + dl)) * cS + s0 + sc4 * 16;
      *(uint4*)dstp       = make_uint4(u[0], u[1], u[2], u[3]);
      *(uint4*)(dstp + 8) = make_uint4(u[4], u[5], u[6], u[7]);
    }

    // ---- compute: 32 x (9 ds_read_b64 + 20 pk_fma) -----------------------
#pragma unroll 4
    for (int k2 = 0; k2 < 32; ++k2) {
      floatx2 xv[4], wv[5];
#pragma unroll
      for (int q = 0; q < 4; ++q)
        xv[q] = *(const floatx2*)&xs[(r0 + q) * K1_XS + 2 * k2];
#pragma unroll
      for (int cc = 0; cc < 5; ++cc)
        wv[cc] = *(const floatx2*)&wsm[(c0 + cc) * K1_XS + 2 * k2];
#pragma unroll
      for (int q = 0; q < 4; ++q)
#pragma unroll
        for (int cc = 0; cc < 5; ++cc)
          acc[q][cc] += xv[q] * wv[cc];
    }
    __syncthreads();
  }

  // ---- epilogue: scaled, biased, transposed stores (float4 over t) -------
#pragma unroll
  for (int cc = 0; cc < 5; ++cc) {
    const int g = c0 + cc;
    const float sc = (g >= 40 && g < 60) ? 2.88539008f : 1.44269504f;
    const float bs = b_ih[g] + b_hh[g];
    float4 v;
    v.x = (acc[0][cc].x + acc[0][cc].y + bs) * sc;
    v.y = (acc[1][cc].x + acc[1][cc].y + bs) * sc;
    v.z = (acc[2][cc].x + acc[2][cc].y + bs) * sc;
    v.w = (acc[3][cc].x + acc[3][cc].y + bs) * sc;
    *(float4*)&xgT[((size_t)(b * cG + g)) * cS + s0 + r0] = v;
  }
}

// ---------------------------------------------------------------------------
// K2: LSTM scan, fully in-register. One wave per batch. (round-2 version,
// measured 184 us; round-3's 2-chains-per-wave experiment got ZERO overlap
// -> reverted. Chain is ~431 cy/step, ~80% stall; batches are CU-parallel so
// only per-step chain surgery can improve this further.)
//
// Lane layout (j = lane&31, clamped to 19):
//   low half  (lane<32):  A-stream = i_j (row j),    B-stream = g_j (row 40+j)
//   high half (lane>=32): A-stream = f_j (row 20+j), B-stream = o_j (row 60+j)
// Streams from xgT are pre-scaled+biased (log2e; 2*log2e for g rows).
// Unified activation: sigmoid = e/(e+1), tanh = (e-1)/(e+1), e = exp2(gate).
//  - gate gather: v_permlane32_swap(act,act): ret.x = low-half bcast (i|g),
//    ret.y = high-half bcast (f|o). Both halves compute c,h redundantly.
//  - h broadcast: 20x v_readlane -> 10 SGPR pairs, fed to v_pk_fma_f32.
// No LDS, no barriers.
// ---------------------------------------------------------------------------
__global__ __launch_bounds__(64) void k2_lstm(
    const float* __restrict__ xgT, const float* __restrict__ W_hh,
    float* __restrict__ hbuf)
{
  const int b    = blockIdx.x;
  const int lane = threadIdx.x;
  const int half = lane >> 5;
  const int l31  = lane & 31;
  const int j    = (l31 < cPE) ? l31 : (cPE - 1);
  const float LOG2E = 1.44269504f, TWOLOG2E = 2.88539008f;

  const int rowA = half ? (20 + j) : j;          // f_j : i_j   (both sigmoid)
  const int rowB = half ? (60 + j) : (40 + j);   // o_j : g_j   (sigmoid : tanh)
  const float sB   = half ? LOG2E : TWOLOG2E;    // pre-scale for W rows
  const float subB = half ? 0.f : 1.f;           // tanh numerator: e-1

  floatx2 wA[10], wB[10];
#pragma unroll
  for (int p = 0; p < 10; ++p) {
    wA[p].x = W_hh[rowA * cPE + 2 * p]     * LOG2E;
    wA[p].y = W_hh[rowA * cPE + 2 * p + 1] * LOG2E;
    wB[p].x = W_hh[rowB * cPE + 2 * p]     * sB;
    wB[p].y = W_hh[rowB * cPE + 2 * p + 1] * sB;
  }

  const float* baseA = xgT + ((size_t)(b * cG + rowA)) * cS;
  const float* baseB = xgT + ((size_t)(b * cG + rowB)) * cS;

  // 4-slot rotation: slot s holds quad q0+s; reload for q+4 (16 steps ahead).
  // Trailing prefetches read <=64B past xgT's end -> hbuf region (safe).
  float4 bufA[4], bufB[4];
#pragma unroll
  for (int s = 0; s < 4; ++s) {
    bufA[s] = *(const float4*)(baseA + s * 4);
    bufB[s] = *(const float4*)(baseB + s * 4);
  }

  // h state lives in SGPR pairs (wave-uniform): hp[p] = {h[2p], h[2p+1]}
  unsigned long long hp[10];
#pragma unroll
  for (int p = 0; p < 10; ++p) hp[p] = 0ull;

  float c = 0.f;
  float* hb = hbuf + (size_t)b * cS * cPE + j;

  for (int q0 = 0; q0 < 256; q0 += 4) {
#pragma unroll
    for (int s = 0; s < 4; ++s) {
      const int q = q0 + s;
      const float4 gA4 = bufA[s];
      const float4 gB4 = bufB[s];
      bufA[s] = *(const float4*)(baseA + (q + 4) * 4);
      bufB[s] = *(const float4*)(baseB + (q + 4) * 4);
#pragma unroll
      for (int e = 0; e < 4; ++e) {
        const float geA = (e == 0) ? gA4.x : (e == 1) ? gA4.y : (e == 2) ? gA4.z : gA4.w;
        const float geB = (e == 0) ? gB4.x : (e == 1) ? gB4.y : (e == 2) ? gB4.z : gB4.w;

        // ---- dots: 20 packed fma, h from SGPR pairs ----------------------
        floatx2 aA0, aA1, aB0, aB1;
        aA0.x = geA; aA0.y = 0.f; aA1.x = 0.f; aA1.y = 0.f;
        aB0.x = geB; aB0.y = 0.f; aB1.x = 0.f; aB1.y = 0.f;
#pragma unroll
        for (int p = 0; p < 5; ++p) {
          asm("v_pk_fma_f32 %0, %1, %2, %0" : "+v"(aA0) : "v"(wA[p]),     "s"(hp[p]));
          asm("v_pk_fma_f32 %0, %1, %2, %0" : "+v"(aA1) : "v"(wA[5 + p]), "s"(hp[5 + p]));
          asm("v_pk_fma_f32 %0, %1, %2, %0" : "+v"(aB0) : "v"(wB[p]),     "s"(hp[p]));
          asm("v_pk_fma_f32 %0, %1, %2, %0" : "+v"(aB1) : "v"(wB[5 + p]), "s"(hp[5 + p]));
        }
        const float gAv = (aA0.x + aA0.y) + (aA1.x + aA1.y);
        const float gBv = (aB0.x + aB0.y) + (aB1.x + aB1.y);

        // ---- activations -------------------------------------------------
        const float eA   = __builtin_amdgcn_exp2f(fminf(gAv, 30.f));
        const float actA = eA * __builtin_amdgcn_rcpf(eA + 1.f);          // sig(i|f)
        const float eB   = __builtin_amdgcn_exp2f(fminf(gBv, 30.f));
        const float actB = (eB - subB) * __builtin_amdgcn_rcpf(eB + 1.f); // tanh(g)|sig(o)

        // ---- half-swap gathers: .x = low bcast (i|g), .y = high (f|o) ----
        union { float f; unsigned u; } ca, cb;
        ca.f = actA; cb.f = actB;
        uintx2 rA = __builtin_amdgcn_permlane32_swap(ca.u, ca.u, false, false);
        uintx2 rB = __builtin_amdgcn_permlane32_swap(cb.u, cb.u, false, false);
        union { unsigned u; float f; } vf, vi, vg, vo;
        vi.u = rA.x; vf.u = rA.y; vg.u = rB.x; vo.u = rB.y;

        // ---- state update (identical on both halves) ---------------------
        c = vf.f * c + vi.f * vg.f;
        const float ec = __builtin_amdgcn_exp2f(fminf(TWOLOG2E * c, 30.f));
        const float th = (ec - 1.f) * __builtin_amdgcn_rcpf(ec + 1.f);
        const float hj = vo.f * th;

        if (lane < cPE) hb[(size_t)(q * 4 + e) * cPE] = hj;

        // ---- broadcast h -> SGPR pairs -----------------------------------
        union { float f; unsigned u; } ch; ch.f = hj;
        const int hbits = (int)ch.u;
        const unsigned l0  = (unsigned)__builtin_amdgcn_readlane(hbits, 0);
        const unsigned l1  = (unsigned)__builtin_amdgcn_readlane(hbits, 1);
        const unsigned l2  = (unsigned)__builtin_amdgcn_readlane(hbits, 2);
        const unsigned l3  = (unsigned)__builtin_amdgcn_readlane(hbits, 3);
        const unsigned l4  = (unsigned)__builtin_amdgcn_readlane(hbits, 4);
        const unsigned l5  = (unsigned)__builtin_amdgcn_readlane(hbits, 5);
        const unsigned l6  = (unsigned)__builtin_amdgcn_readlane(hbits, 6);
        const unsigned l7  = (unsigned)__builtin_amdgcn_readlane(hbits, 7);
        const unsigned l8  = (unsigned)__builtin_amdgcn_readlane(hbits, 8);
        const unsigned l9  = (unsigned)__builtin_amdgcn_readlane(hbits, 9);
        const unsigned l10 = (unsigned)__builtin_amdgcn_readlane(hbits, 10);
        const unsigned l11 = (unsigned)__builtin_amdgcn_readlane(hbits, 11);
        const unsigned l12 = (unsigned)__builtin_amdgcn_readlane(hbits, 12);
        const unsigned l13 = (unsigned)__builtin_amdgcn_readlane(hbits, 13);
        const unsigned l14 = (unsigned)__builtin_amdgcn_readlane(hbits, 14);
        const unsigned l15 = (unsigned)__builtin_amdgcn_readlane(hbits, 15);
        const unsigned l16 = (unsigned)__builtin_amdgcn_readlane(hbits, 16);
        const unsigned l17 = (unsigned)__builtin_amdgcn_readlane(hbits, 17);
        const unsigned l18 = (unsigned)__builtin_amdgcn_readlane(hbits, 18);
        const unsigned l19 = (unsigned)__builtin_amdgcn_readlane(hbits, 19);
        hp[0] = (unsigned long long)l0  | ((unsigned long long)l1  << 32);
        hp[1] = (unsigned long long)l2  | ((unsigned long long)l3  << 32);
        hp[2] = (unsigned long long)l4  | ((unsigned long long)l5  << 32);
        hp[3] = (unsigned long long)l6  | ((unsigned long long)l7  << 32);
        hp[4] = (unsigned long long)l8  | ((unsigned long long)l9  << 32);
        hp[5] = (unsigned long long)l10 | ((unsigned long long)l11 << 32);
        hp[6] = (unsigned long long)l12 | ((unsigned long long)l13 << 32);
        hp[7] = (unsigned long long)l14 | ((unsigned long long)l15 << 32);
        hp[8] = (unsigned long long)l16 | ((unsigned long long)l17 << 32);
        hp[9] = (unsigned long long)l18 | ((unsigned long long)l19 << 32);
      }
    }
  }
}

// ---------------------------------------------------------------------------
// K3a: muwT[g][r] = relu(h@W_mu^T + b_mu), sigma = sigmoid(h@W_sig^T + b_sig)
// SoA output for the scan kernel. Grid: 64 blocks x 256.
// ---------------------------------------------------------------------------
__global__ __launch_bounds__(256) void k3a_muw(
    const float* __restrict__ hbuf,
    const float* __restrict__ W_mu, const float* __restrict__ b_mu,
    const float* __restrict__ W_sig, const float* __restrict__ b_sig,
    float* __restrict__ muwT, float* __restrict__ sigma)
{
  __shared__ float sw[84];
  const int t = threadIdx.x;
  if (t < 60) sw[t] = W_mu[t];
  else if (t < 80) sw[t] = W_sig[t - 60];
  else if (t < 83) sw[t] = b_mu[t - 80];
  else if (t == 83) sw[t] = b_sig[0];
  __syncthreads();

  const int r = blockIdx.x * 256 + t;
  const float4* hp = (const float4*)(hbuf + (size_t)r * cPE);
  float h[20];
#pragma unroll
  for (int q2 = 0; q2 < 5; ++q2) {
    float4 v = hp[q2];
    h[4 * q2] = v.x; h[4 * q2 + 1] = v.y; h[4 * q2 + 2] = v.z; h[4 * q2 + 3] = v.w;
  }
  float m0 = sw[80], m1 = sw[81], m2 = sw[82], sg = sw[83];
#pragma unroll
  for (int p = 0; p < 20; ++p) {
    m0 += sw[p]      * h[p];
    m1 += sw[20 + p] * h[p];
    m2 += sw[40 + p] * h[p];
    sg += sw[60 + p] * h[p];
  }
  muwT[r]                 = fmaxf(m0, 0.f);
  muwT[cB * cS + r]       = fmaxf(m1, 0.f);
  muwT[2 * cB * cS + r]   = fmaxf(m2, 0.f);
  sigma[r] = __builtin_amdgcn_rcpf(1.f + __builtin_amdgcn_exp2f(-1.44269504f * sg));
}

// ---------------------------------------------------------------------------
// K3b: sequential mu recurrence, 16 chains (one lane each).
// Round-4: depth-8 rolling register prefetch (was depth-2, ~100cy cover vs
// ~300-900cy load latency -> per-iter stalls). Distance 8 iters ~ 360cy.
// Slots are compile-time-indexed (inner loop fully unrolled) to avoid
// scratch (runtime-indexed ext_vector arrays -> local memory).
// ---------------------------------------------------------------------------
__global__ __launch_bounds__(64) void k3b_mu(
    const float* __restrict__ muwT, float* __restrict__ mu)
{
  const int t = threadIdx.x;
  if (t >= cB) return;
  const float* s0p = muwT + (size_t)t * cS;
  const float* s1p = muwT + cB * cS + (size_t)t * cS;
  const float* s2p = muwT + 2 * cB * cS + (size_t)t * cS;
  float* mb = mu + (size_t)t * cS;
  const float inv = 1.f / (float)cS;

  float4 b0[8], b1[8], b2[8];
#pragma unroll
  for (int u = 0; u < 8; ++u) {
    b0[u] = *(const float4*)(s0p + u * 4);
    b1[u] = *(const float4*)(s1p + u * 4);
    b2[u] = *(const float4*)(s2p + u * 4);
  }

  float m = 0.f;
  for (int t8 = 0; t8 < 32; ++t8) {
#pragma unroll
    for (int u = 0; u < 8; ++u) {
      const int t4 = t8 * 8 + u;
      float4 w0 = b0[u], w1 = b1[u], w2 = b2[u];
      if (t4 < 248) {
        b0[u] = *(const float4*)(s0p + (t4 + 8) * 4);
        b1[u] = *(const float4*)(s1p + (t4 + 8) * 4);
        b2[u] = *(const float4*)(s2p + (t4 + 8) * 4);
      }
      const int tt = t4 * 4;
      m = w0.x * m + (w1.x + w2.x * (float)(tt + 1)) * inv; mb[tt]     = m;
      m = w0.y * m + (w1.y + w2.y * (float)(tt + 2)) * inv; mb[tt + 1] = m;
      m = w0.z * m + (w1.z + w2.z * (float)(tt + 3)) * inv; mb[tt + 2] = m;
      m = w0.w * m + (w1.w + w2.w * (float)(tt + 4)) * inv; mb[tt + 3] = m;
    }
  }
}

// ---------------------------------------------------------------------------
// K4: fused positional attention with 32x32x16 bf16 MFMA.
// context[b,j,:] = (sum_{i<=j} w_ji * x[b,i,:]) / max(||w_j||, 1e-12)
// x staged d-major in LDS (from xbf_t) so each B-fragment is one
// ds_read_b128. w generated on the fly in MFMA A-fragment layout.
// Block 256 thr = 4 waves: wave = (jh, dh); tile 64 j x 128 d; K-step 32 i.
// Round-4: LDS ping-pong double buffer -> ONE barrier per chunk (was 2) and
// chunk+1 staging issued before chunk's compute (loads in flight under MFMA).
// Safety: reads of buf[pb] and writes of buf[pb^1] share one barrier window
// (disjoint buffers); buf[pb] is rewritten only 2 windows later.
// ---------------------------------------------------------------------------
static constexpr int TJ = 64, TD = 128, KI = 32, RS = 40;  // RS: LDS row stride (shorts)

__global__ __launch_bounds__(256) void k4_attn(
    const float* __restrict__ x, const unsigned short* __restrict__ xbf_t,
    int use_bf, const float* __restrict__ mu, const float* __restrict__ sigma,
    float* __restrict__ out)
{
  __shared__ unsigned short xsT[2][TD * RS];   // 20480 B
  __shared__ float snrm[2][32];
  __shared__ float sscl[2][32];

  const int b   = blockIdx.z;
  const int jt0 = blockIdx.x * TJ;
  const int dt0 = blockIdx.y * TD;
  const int tid = threadIdx.x;
  const int wave = tid >> 6, lane = tid & 63;
  const int jh = wave & 1, dh = wave >> 1;
  const int n32 = lane & 31, half = lane >> 5;
  const int jrow = jt0 + jh * 32 + n32;

  const float muv  = mu[b * cS + jrow];
  const float sg   = sigma[b * cS + jrow];
  const float invj = 1.f / (float)(jrow + 1);
  const float ce   = -0.72134752f / (sg * sg);   // -log2(e)/(2*sigma^2)

  float nrm2 = 0.f;
  floatx16 acc0 = (floatx16)0.f, acc1 = (floatx16)0.f;

  const int iend = jt0 + TJ;

  // ---- staging helper (global -> LDS buf) as a macro-like lambda ---------
  auto stage = [&](int pb, int i0) {
    if (use_bf) {
#pragma unroll
      for (int q = 0; q < 2; ++q) {
        const int cc = tid + q * 256;
        const int dl = cc >> 2, part = cc & 3;
        uint4 v = *(const uint4*)(xbf_t + ((size_t)(b * cD + dt0 + dl)) * cS + i0 + part * 8);
        *(uint4*)&xsT[pb][dl * RS + part * 8] = v;
      }
    } else {
#pragma unroll
      for (int q = 0; q < 2; ++q) {
        const int cc = tid + q * 256;
        const int i = cc & 31, d8 = cc >> 5;
        const float* xp = x + ((size_t)(b * cS + i0 + i)) * cD + dt0 + d8 * 8;
        float4 f0 = *(const float4*)xp;
        float4 f1 = *(const float4*)(xp + 4);
        float vv[8] = {f0.x, f0.y, f0.z, f0.w, f1.x, f1.y, f1.z, f1.w};
#pragma unroll
        for (int e = 0; e < 8; ++e) {
          union { float f; unsigned u; } cv; cv.f = vv[e];
          xsT[pb][(d8 * 8 + e) * RS + i] = (unsigned short)(cv.u >> 16);
        }
      }
    }
  };

  stage(0, 0);
  __syncthreads();

  int pb = 0;
  for (int i0 = 0; i0 < iend; i0 += KI) {
    // ---- issue next chunk's staging early (overlaps with compute) --------
    if (i0 + KI < iend) stage(pb ^ 1, i0 + KI);

    // ---- A fragments (w values), kc = 0,1 --------------------------------
    short8 af0, af1;
#pragma unroll
    for (int kc = 0; kc < 2; ++kc) {
      short8 af;
#pragma unroll
      for (int e = 0; e < 8; ++e) {
        const int ig = i0 + kc * 16 + half * 8 + e;
        const float d = fmaf((float)ig, invj, -muv);
        float w = __builtin_amdgcn_exp2f(ce * d * d);
        w = (ig <= jrow) ? w : 0.f;
        nrm2 += w * w;
        union { float f; unsigned u; } cv; cv.f = w;
        af[e] = (short)(cv.u >> 16);
      }
      if (kc == 0) af0 = af; else af1 = af;
    }

    // ---- B fragments (one ds_read_b128 each) + MFMA ----------------------
    const int rbase = dh * 64 + n32;
    short8 b00 = *(const short8*)&xsT[pb][(rbase)      * RS + half * 8];
    short8 b01 = *(const short8*)&xsT[pb][(rbase)      * RS + 16 + half * 8];
    short8 b10 = *(const short8*)&xsT[pb][(rbase + 32) * RS + half * 8];
    short8 b11 = *(const short8*)&xsT[pb][(rbase + 32) * RS + 16 + half * 8];
    acc0 = __builtin_amdgcn_mfma_f32_32x32x16_bf16(af0, b00, acc0, 0, 0, 0);
    acc0 = __builtin_amdgcn_mfma_f32_32x32x16_bf16(af1, b01, acc0, 0, 0, 0);
    acc1 = __builtin_amdgcn_mfma_f32_32x32x16_bf16(af0, b10, acc1, 0, 0, 0);
    acc1 = __builtin_amdgcn_mfma_f32_32x32x16_bf16(af1, b11, acc1, 0, 0, 0);

    __syncthreads();
    pb ^= 1;
  }

  // ---- norms --------------------------------------------------------------
  nrm2 += __shfl_xor(nrm2, 32);
  if (wave < 2 && half == 0) snrm[jh][n32] = nrm2;
  __syncthreads();
  if (tid < 64)
    sscl[tid >> 5][tid & 31] =
        __builtin_amdgcn_rcpf(fmaxf(sqrtf(snrm[tid >> 5][tid & 31]), 1e-12f));
  __syncthreads();

  float srow[16];
#pragma unroll
  for (int reg = 0; reg < 16; ++reg) {
    const int row = (reg & 3) + 8 * (reg >> 2) + 4 * half;
    srow[reg] = sscl[jh][row];
  }
#pragma unroll
  for (int reg = 0; reg < 16; ++reg) {
    const int row = (reg & 3) + 8 * (reg >> 2) + 4 * half;
    const int jg = jt0 + jh * 32 + row;
    const int d0 = dt0 + dh * 64 + n32;
    out[((size_t)(b * cS + jg)) * cD + d0]      = acc0[reg] * srow[reg];
    out[((size_t)(b * cS + jg)) * cD + d0 + 32] = acc1[reg] * srow[reg];
  }
}

// ---------------------------------------------------------------------------
extern "C" void kernel_launch(void* const* d_in, const int* in_sizes, int n_in,
                              void* d_out, int out_size, void* d_ws, size_t ws_size,
                              hipStream_t stream) {
  const float* x     = (const float*)d_in[0];
  const float* W_ih  = (const float*)d_in[1];
  const float* W_hh  = (const float*)d_in[2];
  const float* b_ih  = (const float*)d_in[3];
  const float* b_hh  = (const float*)d_in[4];
  const float* W_mu  = (const float*)d_in[5];
  const float* b_mu  = (const float*)d_in[6];
  const float* W_sig = (const float*)d_in[7];
  const float* b_sig = (const float*)d_in[8];
  float* out = (float*)d_out;

  char* ws = (char*)d_ws;
  const size_t off_xg  = 0;                                   // 16*80*1024*4
  const size_t off_h   = off_xg  + (size_t)cB*cS*cG*4;
  const size_t off_muw = off_h   + (size_t)cB*cS*cPE*4;
  const size_t off_sig = off_muw + (size_t)cB*cS*3*4;
  const size_t off_mu  = off_sig + (size_t)cB*cS*4;
  const size_t off_xbf = off_mu  + (size_t)cB*cS*4;
  const size_t need_bf = off_xbf + (size_t)cB*cS*cD*2;

  float* xgT   = (float*)(ws + off_xg);
  float* hbuf  = (float*)(ws + off_h);
  float* muwT  = (float*)(ws + off_muw);
  float* sigma = (float*)(ws + off_sig);
  float* mu    = (float*)(ws + off_mu);
  unsigned short* xbf_t = (unsigned short*)(ws + off_xbf);
  const int use_bf = (ws_size >= need_bf) ? 1 : 0;

  k1_xg  <<<dim3(cB * cS / 64), dim3(256), 0, stream>>>(x, W_ih, b_ih, b_hh, xgT, xbf_t, use_bf);
  k2_lstm<<<dim3(cB),           dim3(64),  0, stream>>>(xgT, W_hh, hbuf);
  k3a_muw<<<dim3(cB * cS / 256), dim3(256), 0, stream>>>(hbuf, W_mu, b_mu, W_sig, b_sig, muwT, sigma);
  k3b_mu <<<dim3(1),            dim3(64),  0, stream>>>(muwT, mu);
  k4_attn<<<dim3(cS/TJ, cD/TD, cB), dim3(256), 0, stream>>>(x, xbf_t, use_bf, mu, sigma, out);
}